// Round 5
// baseline (14.163 us; speedup 1.0000x reference)
//
#include <hip/hip_runtime.h>
#include <math.h>

#define NMODES 32
#define INV2PI 0.15915494309189535f

typedef short bf16x8 __attribute__((ext_vector_type(8)));  // 8 bf16 (4 VGPRs)
typedef float f32x4  __attribute__((ext_vector_type(4)));  // MFMA C/D

// sin/cos of (2*pi*rev): v_sin/v_cos take REVOLUTIONS; reduce to [0,1) first.
__device__ inline void sincos_rev(float rev, float& s, float& c) {
    float f = rev - floorf(rev);
    s = __builtin_amdgcn_sinf(f);
    c = __builtin_amdgcn_cosf(f);
}

// Truncation split: x = hi + lo, hi = bf16-truncate(x) (exact residual lo).
__device__ inline void split_bf(float x, short& hi, short& lo) {
    const unsigned u = __float_as_uint(x);
    const float xf = __uint_as_float(u & 0xFFFF0000u);
    hi = (short)(u >> 16);
    const float r = x - xf;                         // exact
    lo = (short)(__float_as_uint(r) >> 16);
}

// One block (4 waves) per h; wave w owns A-slab rows i = r + 16*w.
// K[h, 64*i + d] = 2 * sum_k A[i,k] B[k,d],
//   A[i, m]    =  Re(Ct[m] * exp(dtA[m]*64i)),  A[i, m+32] = -Im(...)
//   B[m, d]    =  Re(exp(dtA[m]*d)),            B[m+32, d] =  Im(...)
// MFMA 16x16x32 bf16 layouts: A[row=lane&15][k=(lane>>4)*8+j],
// B[k=(lane>>4)*8+j][col=lane&15], D[row=(lane>>4)*4+reg][col=lane&15].
// B is a-independent: wave w computes only column-block b=w, shared via LDS.
__global__ __launch_bounds__(256, 4) void ssm_mfma_kernel(
    const float* __restrict__ C_real,      // (H, 32, 2)
    const float* __restrict__ log_dt,      // (H,)
    const float* __restrict__ log_A_real,  // (H, 32)
    const float* __restrict__ A_imag,      // (H, 32)
    float* __restrict__ K,                 // (H, 4096)
    int L)
{
    // [b*4 + q][lane], q = {Bh0,Bl0,Bh1,Bl1}; lane-contiguous 16B = conflict-free b128
    __shared__ bf16x8 ldsB[16][64];

    const int h    = blockIdx.x;
    const int tid  = threadIdx.x;
    const int w    = tid >> 6;             // this wave's a-index AND b-block
    const int lane = tid & 63;
    const int r    = lane & 15;
    const int g    = lane >> 4;            // this lane's 8 modes: g*8 .. g*8+7

    const float dt = __expf(log_dt[h]);

    float dAr_[8], rhi_[8], rlo_[8], Ctr_[8], Cti_[8];

#pragma unroll
    for (int j = 0; j < 8; ++j) {
        const int m   = g * 8 + j;
        const int idx = h * NMODES + m;
        const float Ar = -__expf(log_A_real[idx]);
        const float Ai = A_imag[idx];
        const float dAr = dt * Ar;
        const float dAi_rev = dt * Ai * INV2PI;     // phase step in revolutions

        // exact 12-bit split of the phase step
        const float rhi = __uint_as_float(__float_as_uint(dAi_rev) & 0xFFFFF000u);
        const float rlo = dAi_rev - rhi;            // exact (Sterbenz)

        // Ct = C * (exp(dtA)-1) / A
        float sn, cs;
        sincos_rev(dAi_rev, sn, cs);
        const float er   = __expf(dAr);
        const float em1r = er * cs - 1.0f;
        const float em1i = er * sn;
        const float inv  = 1.0f / (Ar * Ar + Ai * Ai);
        const float fr   = (em1r * Ar + em1i * Ai) * inv;
        const float fi   = (em1i * Ar - em1r * Ai) * inv;
        const float Cr   = C_real[idx * 2 + 0];
        const float Ci   = C_real[idx * 2 + 1];
        Ctr_[j] = Cr * fr - Ci * fi;
        Cti_[j] = Cr * fi + Ci * fr;
        dAr_[j] = dAr; rhi_[j] = rhi; rlo_[j] = rlo;
    }

    // B fragments for this wave's column block b=w: Q[m, d], d = r + 16*w
    {
        bf16x8 bh0, bl0, bh1, bl1;
        const float d = (float)(r + 16 * w);        // < 64: rhi*d exact (12b x 6b)
#pragma unroll
        for (int j = 0; j < 8; ++j) {
            const float pm = __expf(dAr_[j] * d);
            const float p  = rhi_[j] * d;
            const float f  = (p - floorf(p)) + rlo_[j] * d;
            float qs, qc;
            sincos_rev(f, qs, qc);
            short hh, ll;
            split_bf(pm * qc, hh, ll); bh0[j] = hh; bl0[j] = ll;
            split_bf(pm * qs, hh, ll); bh1[j] = hh; bl1[j] = ll;
        }
        ldsB[w * 4 + 0][lane] = bh0;
        ldsB[w * 4 + 1][lane] = bl0;
        ldsB[w * 4 + 2][lane] = bh1;
        ldsB[w * 4 + 3][lane] = bl1;
    }

    // A fragments for this wave's slab a=w: G = Ct * exp(dtA * 64*(r+16w))
    bf16x8 Ah0, Al0, Ah1, Al1;
    {
        const float t = (float)(64 * (r + 16 * w));  // <= 4032, 6 sig bits
#pragma unroll
        for (int j = 0; j < 8; ++j) {
            const float pm = __expf(dAr_[j] * t);
            const float p  = rhi_[j] * t;            // exact (12b x 6b)
            const float f  = (p - floorf(p)) + rlo_[j] * t;  // rlo*t exact
            float zs, zc;
            sincos_rev(f, zs, zc);
            const float gr  = (Ctr_[j] * zc - Cti_[j] * zs) * pm;
            const float gni = -(Ctr_[j] * zs + Cti_[j] * zc) * pm;
            short hh, ll;
            split_bf(gr, hh, ll);  Ah0[j] = hh; Al0[j] = ll;
            split_bf(gni, hh, ll); Ah1[j] = hh; Al1[j] = ll;
        }
    }

    __syncthreads();

    float* __restrict__ Kh = K + (size_t)h * L;

#pragma unroll
    for (int b = 0; b < 4; ++b) {
        const bf16x8 Bh0 = ldsB[b * 4 + 0][lane];
        const bf16x8 Bl0 = ldsB[b * 4 + 1][lane];
        const bf16x8 Bh1 = ldsB[b * 4 + 2][lane];
        const bf16x8 Bl1 = ldsB[b * 4 + 3][lane];
        f32x4 acc = {0.f, 0.f, 0.f, 0.f};
        // hi*hi + hi*lo + lo*hi (lo*lo dropped, ~2^-18)
        acc = __builtin_amdgcn_mfma_f32_16x16x32_bf16(Ah0, Bh0, acc, 0, 0, 0);
        acc = __builtin_amdgcn_mfma_f32_16x16x32_bf16(Ah1, Bh1, acc, 0, 0, 0);
        acc = __builtin_amdgcn_mfma_f32_16x16x32_bf16(Ah0, Bl0, acc, 0, 0, 0);
        acc = __builtin_amdgcn_mfma_f32_16x16x32_bf16(Ah1, Bl1, acc, 0, 0, 0);
        acc = __builtin_amdgcn_mfma_f32_16x16x32_bf16(Al0, Bh0, acc, 0, 0, 0);
        acc = __builtin_amdgcn_mfma_f32_16x16x32_bf16(Al1, Bh1, acc, 0, 0, 0);
        // D[row = 4g + reg][col = r] -> K[64*(16w + 4g + reg) + 16b + r]
#pragma unroll
        for (int reg = 0; reg < 4; ++reg) {
            Kh[64 * (16 * w + 4 * g + reg) + 16 * b + r] = 2.0f * acc[reg];
        }
    }
}

extern "C" void kernel_launch(void* const* d_in, const int* in_sizes, int n_in,
                              void* d_out, int out_size, void* d_ws, size_t ws_size,
                              hipStream_t stream) {
    const float* C_real     = (const float*)d_in[0];
    const float* log_dt     = (const float*)d_in[1];
    const float* log_A_real = (const float*)d_in[2];
    const float* A_imag     = (const float*)d_in[3];
    float* K = (float*)d_out;

    const int H = in_sizes[1];            // log_dt has H elements
    const int L = out_size / H;           // 4096

    ssm_mfma_kernel<<<H, 256, 0, stream>>>(
        C_real, log_dt, log_A_real, A_imag, K, L);
}